// Round 3
// baseline (247.564 us; speedup 1.0000x reference)
//
#include <hip/hip_runtime.h>

// LSTM: T=512, B=4096, IN=1, H=12.
// R3: h exchange via ds_bpermute (in-register crossbar, no LDS roundtrip on
// the critical path) + v_pk_fma_f32 packed gate dots (gates paired (i,f) and
// (g,o); 24 pk-FMA instead of 48 scalar FMA). 1 thread per (cell, j); 5
// cells/wave; single-wave blocks, barrier-free. X staged to LDS per 64 steps.

#define TT    512
#define NB    4096
#define HH    12
#define CPB   5      // cells per block (one wave, 60 active lanes)
#define CHUNK 64     // X staging chunk; TT % CHUNK == 0

typedef float v2f __attribute__((ext_vector_type(2)));

static __device__ __forceinline__ v2f pkfma(v2f a, v2f b, v2f c) {
#if __has_builtin(__builtin_elementwise_fma)
    return __builtin_elementwise_fma(a, b, c);
#else
    v2f r; r.x = fmaf(a.x, b.x, c.x); r.y = fmaf(a.y, b.y, c.y); return r;
#endif
}

__device__ __forceinline__ float sigm(float x) {
    return __builtin_amdgcn_rcpf(1.0f + __builtin_amdgcn_exp2f(-1.4426950408889634f * x));
}
__device__ __forceinline__ float tanh_fast(float x) {
    return 1.0f - 2.0f * __builtin_amdgcn_rcpf(1.0f + __builtin_amdgcn_exp2f(2.8853900817779268f * x));
}

__global__ __launch_bounds__(64)
void lstm_fused(const float* __restrict__ X,
                const float* __restrict__ W_ih,
                const float* __restrict__ W_hh,
                const float* __restrict__ b_ih,
                const float* __restrict__ b_hh,
                const float* __restrict__ fc_w,
                const float* __restrict__ fc_b,
                float* __restrict__ out)
{
    __shared__ float xchunk[CHUNK][CPB];

    const int lane = threadIdx.x;            // 0..63
    const int c0   = lane / HH;              // 0..4 valid, 5 for idle lanes
    const int j    = lane - c0 * HH;         // 0..11
    const int cs   = (c0 > CPB - 1) ? 0 : c0;   // clamped cell slot
    const int cellbase = blockIdx.x * CPB;
    const int cell = cellbase + cs;
    const bool active  = (lane < CPB * HH) && (cell < NB);
    const bool outlane = active && (j == 0);

    // bpermute source addresses for gathering h of my cell (loop-invariant)
    int paddr[HH];
    #pragma unroll
    for (int k = 0; k < HH; ++k) paddr[k] = (cs * HH + k) * 4;

    // packed recurrent weights: wif[k] = (W_i[j][k], W_f[j][k]), wgo likewise
    v2f wif[HH], wgo[HH];
    float fcw[HH];
    #pragma unroll
    for (int k = 0; k < HH; ++k) {
        wif[k].x = W_hh[(0 * HH + j) * HH + k];
        wif[k].y = W_hh[(1 * HH + j) * HH + k];
        wgo[k].x = W_hh[(2 * HH + j) * HH + k];
        wgo[k].y = W_hh[(3 * HH + j) * HH + k];
        fcw[k] = fc_w[k];
    }
    v2f bif, bgo, wxif, wxgo;
    bif.x  = b_ih[0 * HH + j] + b_hh[0 * HH + j];
    bif.y  = b_ih[1 * HH + j] + b_hh[1 * HH + j];
    bgo.x  = b_ih[2 * HH + j] + b_hh[2 * HH + j];
    bgo.y  = b_ih[3 * HH + j] + b_hh[3 * HH + j];
    wxif.x = W_ih[0 * HH + j];   // IN == 1, W_ih flat [48]
    wxif.y = W_ih[1 * HH + j];
    wxgo.x = W_ih[2 * HH + j];
    wxgo.y = W_ih[3 * HH + j];
    const float fcb = fc_b[0];

    float cst = 0.0f;     // cell state c[cell][j]
    float hv[HH];         // gathered h of my cell (h_{t-1}); h0 = 0
    #pragma unroll
    for (int k = 0; k < HH; ++k) hv[k] = 0.0f;

    #pragma unroll 2
    for (int t = 0; t < TT; ++t) {
        // stage X[t .. t+CHUNK) for this block's cells into LDS
        if ((t & (CHUNK - 1)) == 0) {
            const int tt = t + lane;   // CHUNK == 64 == wave size
            #pragma unroll
            for (int k = 0; k < CPB; ++k) {
                const int cc = cellbase + k;
                xchunk[lane][k] = (cc < NB) ? X[tt * NB + cc] : 0.0f;
            }
        }

        // x value for this step (broadcast within cell; off critical path)
        const float xv = xchunk[t & (CHUNK - 1)][cs];

        // fc output for step t-1 (hv currently holds h_{t-1})
        if (t > 0 && outlane) {
            float acc = fcb;
            #pragma unroll
            for (int k = 0; k < HH; ++k) acc = fmaf(hv[k], fcw[k], acc);
            out[(t - 1) * NB + cell] = acc;
        }

        // gates: packed (i,f) and (g,o) accumulators, 24 pk-FMA total
        v2f xvv; xvv.x = xv; xvv.y = xv;
        v2f gif = pkfma(xvv, wxif, bif);
        v2f ggo = pkfma(xvv, wxgo, bgo);
        #pragma unroll
        for (int k = 0; k < HH; ++k) {
            v2f hk; hk.x = hv[k]; hk.y = hv[k];
            gif = pkfma(wif[k], hk, gif);
            ggo = pkfma(wgo[k], hk, ggo);
        }
        const float si = sigm(gif.x);
        const float sf = sigm(gif.y);
        const float tg = tanh_fast(ggo.x);
        const float so = sigm(ggo.y);
        cst = fmaf(sf, cst, si * tg);
        const float hn = so * tanh_fast(cst);

        // exchange h_t cross-lane: hv[k] = hn of lane (cs*12 + k)
        const int hbits = __float_as_int(hn);
        #pragma unroll
        for (int k = 0; k < HH; ++k)
            hv[k] = __int_as_float(__builtin_amdgcn_ds_bpermute(paddr[k], hbits));
    }

    // final output for t = TT-1 (hv now holds h_{TT-1})
    if (outlane) {
        float acc = fcb;
        #pragma unroll
        for (int k = 0; k < HH; ++k) acc = fmaf(hv[k], fcw[k], acc);
        out[(TT - 1) * NB + cell] = acc;
    }
}

extern "C" void kernel_launch(void* const* d_in, const int* in_sizes, int n_in,
                              void* d_out, int out_size, void* d_ws, size_t ws_size,
                              hipStream_t stream) {
    const float* X    = (const float*)d_in[0];
    const float* W_ih = (const float*)d_in[1];
    const float* W_hh = (const float*)d_in[2];
    const float* b_ih = (const float*)d_in[3];
    const float* b_hh = (const float*)d_in[4];
    const float* fc_w = (const float*)d_in[5];
    const float* fc_b = (const float*)d_in[6];
    float* out = (float*)d_out;

    const int grid = (NB + CPB - 1) / CPB;   // 820 blocks of 1 wave
    lstm_fused<<<grid, 64, 0, stream>>>(X, W_ih, W_hh, b_ih, b_hh, fc_w, fc_b, out);
}